// Round 2
// baseline (155.755 us; speedup 1.0000x reference)
//
#include <hip/hip_runtime.h>

// LPSC cell: per-row tiny MLP. c == 0.0 in the reference, so the g-branch
// (wfa/wfb/wfc) is dead: new_S = Y + (-Y + k1*x1 - k2*x2) exactly.
// Memory-bound: 60 B/row * 2^21 rows ~= 126 MB -> ~20 us floor at 6.3 TB/s.
// Each thread owns R=4 CONSECUTIVE rows so every global access is float4.

#define LDIM 5
#define HDIM 16

constexpr int BLOCK = 256;
constexpr int R = 4;  // consecutive rows per thread -> all loads/stores dwordx4

__global__ __launch_bounds__(BLOCK) void lpsc_kernel(
    const float* __restrict__ inputs,  // (B,2)
    const float* __restrict__ Zin,     // (B,5)
    const float* __restrict__ Yin,     // (B,1)
    const float* __restrict__ A,       // (5,5)
    const float* __restrict__ w2a,     // (5,16)
    const float* __restrict__ b2a,     // (16,)
    const float* __restrict__ w2b,     // (16,16)
    const float* __restrict__ b2b,     // (16,)
    const float* __restrict__ w2c,     // (16,2)
    const float* __restrict__ b2c,     // (2,)
    float* __restrict__ out,           // [B: newS][5B: newZ][B: newS]
    int B)
{
    __shared__ float sA[LDIM * LDIM];
    __shared__ float sW1[LDIM * HDIM];
    __shared__ float sB1[HDIM];
    __shared__ float sW2[HDIM * HDIM];
    __shared__ float sB2[HDIM];
    __shared__ float sW3[HDIM * 2];
    __shared__ float sB3[2];

    const int t = threadIdx.x;
    if (t < LDIM * LDIM) sA[t] = A[t];
    if (t < LDIM * HDIM) sW1[t] = w2a[t];
    if (t < HDIM)        sB1[t] = b2a[t];
    if (t < HDIM * HDIM) sW2[t] = w2b[t];
    if (t < HDIM)        sB2[t] = b2b[t];
    if (t < HDIM * 2)    sW3[t] = w2c[t];
    if (t < 2)           sB3[t] = b2c[t];
    __syncthreads();

    const long long g = (long long)blockIdx.x * BLOCK + t;  // thread id
    const long long r0 = g * R;                             // first of 4 rows
    if (r0 >= B) return;
    const bool full = (r0 + R <= B);

    float z[R][LDIM];
    float x1[R], x2[R], y[R];

    if (full) {
        // inputs: 8 consecutive floats
        const float4 iv0 = reinterpret_cast<const float4*>(inputs)[g * 2 + 0];
        const float4 iv1 = reinterpret_cast<const float4*>(inputs)[g * 2 + 1];
        x1[0] = iv0.x; x2[0] = iv0.y; x1[1] = iv0.z; x2[1] = iv0.w;
        x1[2] = iv1.x; x2[2] = iv1.y; x1[3] = iv1.z; x2[3] = iv1.w;
        // Y: 4 consecutive floats
        const float4 yv = reinterpret_cast<const float4*>(Yin)[g];
        y[0] = yv.x; y[1] = yv.y; y[2] = yv.z; y[3] = yv.w;
        // Z: 20 consecutive floats
        float zf[R * LDIM];
        #pragma unroll
        for (int q = 0; q < 5; ++q) {
            const float4 zv = reinterpret_cast<const float4*>(Zin)[g * 5 + q];
            zf[q * 4 + 0] = zv.x; zf[q * 4 + 1] = zv.y;
            zf[q * 4 + 2] = zv.z; zf[q * 4 + 3] = zv.w;
        }
        #pragma unroll
        for (int r = 0; r < R; ++r)
            #pragma unroll
            for (int k = 0; k < LDIM; ++k) z[r][k] = zf[r * LDIM + k];
    } else {
        #pragma unroll
        for (int r = 0; r < R; ++r) {
            long long rr = (r0 + r < B) ? (r0 + r) : (long long)(B - 1);
            x1[r] = inputs[rr * 2 + 0];
            x2[r] = inputs[rr * 2 + 1];
            y[r]  = Yin[rr];
            #pragma unroll
            for (int k = 0; k < LDIM; ++k) z[r][k] = Zin[rr * LDIM + k];
        }
    }

    // new_Z = Z @ A
    float nz[R][LDIM];
    #pragma unroll
    for (int r = 0; r < R; ++r)
        #pragma unroll
        for (int j = 0; j < LDIM; ++j) nz[r][j] = 0.0f;
    #pragma unroll
    for (int k = 0; k < LDIM; ++k)
        #pragma unroll
        for (int j = 0; j < LDIM; ++j) {
            const float a = sA[k * LDIM + j];
            #pragma unroll
            for (int r = 0; r < R; ++r) nz[r][j] = fmaf(z[r][k], a, nz[r][j]);
        }

    // h = relu(new_Z @ w2a + b2a)
    float h[R][HDIM];
    #pragma unroll
    for (int r = 0; r < R; ++r)
        #pragma unroll
        for (int j = 0; j < HDIM; ++j) h[r][j] = sB1[j];
    #pragma unroll
    for (int k = 0; k < LDIM; ++k)
        #pragma unroll
        for (int j = 0; j < HDIM; ++j) {
            const float w = sW1[k * HDIM + j];
            #pragma unroll
            for (int r = 0; r < R; ++r) h[r][j] = fmaf(nz[r][k], w, h[r][j]);
        }
    #pragma unroll
    for (int r = 0; r < R; ++r)
        #pragma unroll
        for (int j = 0; j < HDIM; ++j) h[r][j] = fmaxf(h[r][j], 0.0f);

    // g2 = relu(h @ w2b + b2b)
    float g2[R][HDIM];
    #pragma unroll
    for (int r = 0; r < R; ++r)
        #pragma unroll
        for (int j = 0; j < HDIM; ++j) g2[r][j] = sB2[j];
    #pragma unroll
    for (int k = 0; k < HDIM; ++k)
        #pragma unroll
        for (int j = 0; j < HDIM; ++j) {
            const float w = sW2[k * HDIM + j];
            #pragma unroll
            for (int r = 0; r < R; ++r) g2[r][j] = fmaf(h[r][k], w, g2[r][j]);
        }
    #pragma unroll
    for (int r = 0; r < R; ++r)
        #pragma unroll
        for (int j = 0; j < HDIM; ++j) g2[r][j] = fmaxf(g2[r][j], 0.0f);

    // K = |g2 @ w2c + b2c|
    float k1[R], k2[R];
    #pragma unroll
    for (int r = 0; r < R; ++r) { k1[r] = sB3[0]; k2[r] = sB3[1]; }
    #pragma unroll
    for (int k = 0; k < HDIM; ++k) {
        const float w0 = sW3[k * 2 + 0];
        const float w1 = sW3[k * 2 + 1];
        #pragma unroll
        for (int r = 0; r < R; ++r) {
            k1[r] = fmaf(g2[r][k], w0, k1[r]);
            k2[r] = fmaf(g2[r][k], w1, k2[r]);
        }
    }

    float ns[R];
    #pragma unroll
    for (int r = 0; r < R; ++r) {
        const float K1 = fabsf(k1[r]);
        const float K2 = fabsf(k2[r]);
        // DY = -Y + k1*x1 - k2*x2 (+ 0*g); new_S = Y + DY (ref op order)
        const float dy = -y[r] + K1 * x1[r] - K2 * x2[r];
        ns[r] = y[r] + dy;
    }

    if (full) {
        float4 nsv = make_float4(ns[0], ns[1], ns[2], ns[3]);
        reinterpret_cast<float4*>(out)[g] = nsv;
        reinterpret_cast<float4*>(out + (long long)6 * B)[g] = nsv;
        float zf[R * LDIM];
        #pragma unroll
        for (int r = 0; r < R; ++r)
            #pragma unroll
            for (int j = 0; j < LDIM; ++j) zf[r * LDIM + j] = nz[r][j];
        #pragma unroll
        for (int q = 0; q < 5; ++q) {
            reinterpret_cast<float4*>(out + (long long)B)[g * 5 + q] =
                make_float4(zf[q * 4 + 0], zf[q * 4 + 1], zf[q * 4 + 2], zf[q * 4 + 3]);
        }
    } else {
        #pragma unroll
        for (int r = 0; r < R; ++r) {
            const long long row = r0 + r;
            if (row < B) {
                out[row] = ns[r];
                out[(long long)6 * B + row] = ns[r];
                #pragma unroll
                for (int j = 0; j < LDIM; ++j)
                    out[(long long)B + row * LDIM + j] = nz[r][j];
            }
        }
    }
}

extern "C" void kernel_launch(void* const* d_in, const int* in_sizes, int n_in,
                              void* d_out, int out_size, void* d_ws, size_t ws_size,
                              hipStream_t stream) {
    const float* inputs = (const float*)d_in[0];
    const float* Zin    = (const float*)d_in[1];
    const float* Yin    = (const float*)d_in[2];
    const float* A      = (const float*)d_in[3];
    const float* w2a    = (const float*)d_in[4];
    const float* b2a    = (const float*)d_in[5];
    const float* w2b    = (const float*)d_in[6];
    const float* b2b    = (const float*)d_in[7];
    const float* w2c    = (const float*)d_in[8];
    const float* b2c    = (const float*)d_in[9];

    const int B = in_sizes[2];  // Y has B elements
    const int rowsPerBlock = BLOCK * R;
    const int grid = (B + rowsPerBlock - 1) / rowsPerBlock;

    lpsc_kernel<<<grid, BLOCK, 0, stream>>>(inputs, Zin, Yin, A, w2a, b2a,
                                            w2b, b2b, w2c, b2c,
                                            (float*)d_out, B);
}